// Round 1
// baseline (170.579 us; speedup 1.0000x reference)
//
#include <hip/hip_runtime.h>

// ContrastiveEmbeddingLoss (N=8192, D=128, T=0.5) — fused MFMA implementation.
//
// Pipeline (all on `stream`):
//   0) hipMemsetAsync: zero label counters + loss accumulators (24 B of ws)
//   1) prep_kernel:  fp32 E -> bf16 hi/lo split arrays (near-fp32 fidelity:
//                    hi*hi + hi*lo + lo*hi), + label histogram (atomics)
//   2) sim_kernel:   fused E·E^T/T + online softmax (per-row max, exp-sums of
//                    pos/all-nondiag). 64 row-blocks x 8 col-splits = 512 blocks,
//                    4 waves/block, 32 rows/wave held in registers; column tiles
//                    double-buffered in LDS with XOR-16B swizzle (conflict-free
//                    ds_read_b128). Swapped MFMA operands so sim rows are
//                    lane-local (softmax state per-lane, no per-tile shuffles).
//   3) merge_kernel: combine the 8 column-split partials per row (log-sum-exp
//                    merge), per-row loss, block reduce, atomicAdd.
//   4) final_kernel: mean over valid rows -> d_out[0].

#define NROWS 8192
#define DDIM  128
#define INV_T 2.0f
#define EPSV  1e-8f

#define BN     32                 // cols per LDS tile
#define ROWB   128                // rows per block (4 waves x 32)
#define CSPLIT 8                  // column splits (grid.y)
#define CPB    (NROWS / CSPLIT)   // 1024 cols per block
#define NT     (CPB / BN)         // 32 tiles per block

typedef short bf16x8 __attribute__((ext_vector_type(8)));
typedef float f32x4  __attribute__((ext_vector_type(4)));
typedef int   i32x4  __attribute__((ext_vector_type(4)));
typedef unsigned short u16;
typedef unsigned int   u32;

__device__ __forceinline__ u16 f2bf(float f) {  // round-to-nearest-even
  u32 u = __float_as_uint(f);
  u32 r = u + 0x7fffu + ((u >> 16) & 1u);
  return (u16)(r >> 16);
}
__device__ __forceinline__ float bf2f(u16 h) {
  return __uint_as_float(((u32)h) << 16);
}

__global__ __launch_bounds__(256) void prep_kernel(
    const float* __restrict__ emb, const int* __restrict__ labels,
    u16* __restrict__ ehi, u16* __restrict__ elo, int* __restrict__ cnt) {
  const int tid = blockIdx.x * 256 + threadIdx.x;       // 131072 threads, 8 elems each
  const float4* src = ((const float4*)emb) + (size_t)tid * 2;
  float4 a = src[0], b = src[1];
  float v[8] = {a.x, a.y, a.z, a.w, b.x, b.y, b.z, b.w};
  union { u16 us[8]; bf16x8 v8; } hv, lv;
#pragma unroll
  for (int i = 0; i < 8; ++i) {
    float f  = v[i];
    u16 hb   = f2bf(f);
    hv.us[i] = hb;
    lv.us[i] = f2bf(f - bf2f(hb));
  }
  *(bf16x8*)(ehi + (size_t)tid * 8) = hv.v8;
  *(bf16x8*)(elo + (size_t)tid * 8) = lv.v8;
  if (tid < NROWS) atomicAdd(&cnt[labels[tid] + 1], 1);
}

__global__ __launch_bounds__(256, 2) void sim_kernel(
    const u16* __restrict__ ehi, const u16* __restrict__ elo,
    const int* __restrict__ labels,
    float* __restrict__ pm, float* __restrict__ ps, float* __restrict__ pp) {

  __shared__ __align__(16) u16 lhi[2][BN * DDIM];   // 2 x 8 KB
  __shared__ __align__(16) u16 llo[2][BN * DDIM];   // 2 x 8 KB
  __shared__ __align__(16) int llab[2][BN];

  const int tid  = threadIdx.x;
  const int lane = tid & 63;
  const int l15  = lane & 15;
  const int lq   = lane >> 4;            // 0..3 (k-quarter / j-group)
  const int wave = tid >> 6;

  const int wrow0 = blockIdx.x * ROWB + wave * 32;   // this wave's 32 rows
  const int col0  = blockIdx.y * CPB;

  // ---- row fragments (MFMA B operand), resident in registers for all tiles ----
  // B[k][n]: n = lane&15 (row within 16-row subtile rt), k = kc*32 + lq*8 + i
  bf16x8 rh[2][4], rl[2][4];
#pragma unroll
  for (int rt = 0; rt < 2; ++rt) {
    const u16* bh = ehi + (size_t)(wrow0 + rt * 16 + l15) * DDIM + lq * 8;
    const u16* bl = elo + (size_t)(wrow0 + rt * 16 + l15) * DDIM + lq * 8;
#pragma unroll
    for (int kc = 0; kc < 4; ++kc) {
      rh[rt][kc] = *(const bf16x8*)(bh + kc * 32);
      rl[rt][kc] = *(const bf16x8*)(bl + kc * 32);
    }
  }

  const int li0 = labels[wrow0 + l15];        // anchor labels for my 2 rows
  const int li1 = labels[wrow0 + 16 + l15];

  // ---- staging addressing: logical tile layout [32 cols][128 k] bf16 (8 KB).
  // Swizzle: stored byte = logical byte ^ ((col&15)<<4). Thread handles 2 16B
  // chunks per array (chunk z at logical tid*16 + z*4096).
  const int c0    = tid >> 4;                 // col of chunk 0 (chunk 1: +16)
  const int slot  = tid & 15;                 // 16B slot within col
  const u32 d0    = ((u32)(tid * 16)) ^ ((u32)((c0 & 15) << 4));
  const int goff0 = c0 * DDIM + slot * 8;     // element offset within tile rows
  const int goff1 = goff0 + 16 * DDIM;

  // ---- LDS read addressing (A-frag: m = lane&15 = local col, k = kc*32+lq*8+i)
  const u32 swzb  = (u32)(l15 << 4);
  const u32 rbase = (u32)(l15 * 256 + lq * 16);

  // per-lane online-softmax state for rows (wrow0+l15) and (wrow0+16+l15),
  // covering only this lane's j-subset; merged across lq at the end.
  float m0 = -3.0e38f, m1 = -3.0e38f;
  float S0 = 0.f, S1 = 0.f, P0 = 0.f, P1 = 0.f;

  bf16x8 gh0, gh1, gl0, gl1;
  int glab = 0;

  // prologue: stage tile 0
  {
    const int cb = col0;
    gh0 = *(const bf16x8*)(ehi + (size_t)cb * DDIM + goff0);
    gh1 = *(const bf16x8*)(ehi + (size_t)cb * DDIM + goff1);
    gl0 = *(const bf16x8*)(elo + (size_t)cb * DDIM + goff0);
    gl1 = *(const bf16x8*)(elo + (size_t)cb * DDIM + goff1);
    if (tid < BN) glab = labels[cb + tid];
    *(bf16x8*)((char*)(&lhi[0][0]) + d0)         = gh0;
    *(bf16x8*)((char*)(&lhi[0][0]) + d0 + 4096u) = gh1;
    *(bf16x8*)((char*)(&llo[0][0]) + d0)         = gl0;
    *(bf16x8*)((char*)(&llo[0][0]) + d0 + 4096u) = gl1;
    if (tid < BN) llab[0][tid] = glab;
  }
  __syncthreads();

  int bufi = 0;
#pragma unroll 1
  for (int t = 0; t < NT; ++t) {
    const int cb = col0 + t * BN;
    const bool hasnext = (t + 1 < NT);
    if (hasnext) {   // async-stage: issue next tile's global loads before compute
      const int cbn = cb + BN;
      gh0 = *(const bf16x8*)(ehi + (size_t)cbn * DDIM + goff0);
      gh1 = *(const bf16x8*)(ehi + (size_t)cbn * DDIM + goff1);
      gl0 = *(const bf16x8*)(elo + (size_t)cbn * DDIM + goff0);
      gl1 = *(const bf16x8*)(elo + (size_t)cbn * DDIM + goff1);
      if (tid < BN) glab = labels[cbn + tid];
    }

    const char* ph = (const char*)(&lhi[bufi][0]);
    const char* pl = (const char*)(&llo[bufi][0]);
    const i32x4 labq0 = *(const i32x4*)(&llab[bufi][lq * 4]);
    const i32x4 labq1 = *(const i32x4*)(&llab[bufi][16 + lq * 4]);

    f32x4 acc00 = {0.f, 0.f, 0.f, 0.f};   // acc[ct][rt]: D[j'][r] (transposed sim tile)
    f32x4 acc01 = {0.f, 0.f, 0.f, 0.f};
    f32x4 acc10 = {0.f, 0.f, 0.f, 0.f};
    f32x4 acc11 = {0.f, 0.f, 0.f, 0.f};

#pragma unroll
    for (int kc = 0; kc < 4; ++kc) {
      const u32 o0 = (rbase + (u32)(kc * 64)) ^ swzb;
      const u32 o1 = o0 + 4096u;                       // ct=1: +16 cols
      const bf16x8 ah0 = *(const bf16x8*)(ph + o0);
      const bf16x8 ah1 = *(const bf16x8*)(ph + o1);
      const bf16x8 al0 = *(const bf16x8*)(pl + o0);
      const bf16x8 al1 = *(const bf16x8*)(pl + o1);
      // split-bf16: hi_c*hi_r + lo_c*hi_r + hi_c*lo_r  (lo*lo dropped, ~2^-16)
      acc00 = __builtin_amdgcn_mfma_f32_16x16x32_bf16(ah0, rh[0][kc], acc00, 0, 0, 0);
      acc01 = __builtin_amdgcn_mfma_f32_16x16x32_bf16(ah0, rh[1][kc], acc01, 0, 0, 0);
      acc10 = __builtin_amdgcn_mfma_f32_16x16x32_bf16(ah1, rh[0][kc], acc10, 0, 0, 0);
      acc11 = __builtin_amdgcn_mfma_f32_16x16x32_bf16(ah1, rh[1][kc], acc11, 0, 0, 0);
      acc00 = __builtin_amdgcn_mfma_f32_16x16x32_bf16(al0, rh[0][kc], acc00, 0, 0, 0);
      acc01 = __builtin_amdgcn_mfma_f32_16x16x32_bf16(al0, rh[1][kc], acc01, 0, 0, 0);
      acc10 = __builtin_amdgcn_mfma_f32_16x16x32_bf16(al1, rh[0][kc], acc10, 0, 0, 0);
      acc11 = __builtin_amdgcn_mfma_f32_16x16x32_bf16(al1, rh[1][kc], acc11, 0, 0, 0);
      acc00 = __builtin_amdgcn_mfma_f32_16x16x32_bf16(ah0, rl[0][kc], acc00, 0, 0, 0);
      acc01 = __builtin_amdgcn_mfma_f32_16x16x32_bf16(ah0, rl[1][kc], acc01, 0, 0, 0);
      acc10 = __builtin_amdgcn_mfma_f32_16x16x32_bf16(ah1, rl[0][kc], acc10, 0, 0, 0);
      acc11 = __builtin_amdgcn_mfma_f32_16x16x32_bf16(ah1, rl[1][kc], acc11, 0, 0, 0);
    }

    // ---- online softmax update (per-lane, per row-subtile) ----
    float sv[2][2][4];
#pragma unroll
    for (int q = 0; q < 4; ++q) {
      sv[0][0][q] = acc00[q] * INV_T;
      sv[0][1][q] = acc01[q] * INV_T;
      sv[1][0][q] = acc10[q] * INV_T;
      sv[1][1][q] = acc11[q] * INV_T;
    }
    float tm0 = sv[0][0][0], tm1 = sv[0][1][0];
#pragma unroll
    for (int q = 0; q < 4; ++q) {
      tm0 = fmaxf(tm0, fmaxf(sv[0][0][q], sv[1][0][q]));
      tm1 = fmaxf(tm1, fmaxf(sv[0][1][q], sv[1][1][q]));
    }
    const float nm0 = fmaxf(m0, tm0), nm1 = fmaxf(m1, tm1);
    const float rs0 = __expf(m0 - nm0), rs1 = __expf(m1 - nm1);
    S0 *= rs0; P0 *= rs0; m0 = nm0;
    S1 *= rs1; P1 *= rs1; m1 = nm1;

    const bool dt = (cb == wrow0);     // 32-aligned equal ranges: diag iff equal
#pragma unroll
    for (int ct = 0; ct < 2; ++ct) {
#pragma unroll
      for (int q = 0; q < 4; ++q) {
        const int jl = ct * 16 + lq * 4 + q;                // local col in tile
        const int lj = (ct == 0) ? labq0[q] : labq1[q];
        {
          const float e  = __expf(sv[ct][0][q] - m0);
          const bool nd  = !(dt && (jl == l15));            // exclude diagonal
          const bool pb  = ((li0 == 0) || (lj == 0) || (lj == li0)) && nd;
          S0 += nd ? e : 0.f;
          P0 += pb ? e : 0.f;
        }
        {
          const float e  = __expf(sv[ct][1][q] - m1);
          const bool nd  = !(dt && (jl == 16 + l15));
          const bool pb  = ((li1 == 0) || (lj == 0) || (lj == li1)) && nd;
          S1 += nd ? e : 0.f;
          P1 += pb ? e : 0.f;
        }
      }
    }

    if (hasnext) {   // write next tile into the other buffer (safe: all waves
                     // finished reading it before the previous barrier)
      char* wh = (char*)(&lhi[bufi ^ 1][0]);
      char* wl = (char*)(&llo[bufi ^ 1][0]);
      *(bf16x8*)(wh + d0)         = gh0;
      *(bf16x8*)(wh + d0 + 4096u) = gh1;
      *(bf16x8*)(wl + d0)         = gl0;
      *(bf16x8*)(wl + d0 + 4096u) = gl1;
      if (tid < BN) llab[bufi ^ 1][tid] = glab;
    }
    __syncthreads();
    bufi ^= 1;
  }

  // ---- merge the 4 lane-groups (lq) holding disjoint j-subsets of each row ----
#pragma unroll
  for (int off = 16; off <= 32; off <<= 1) {
    const float mo0 = __shfl_xor(m0, off), So0 = __shfl_xor(S0, off), Po0 = __shfl_xor(P0, off);
    const float mo1 = __shfl_xor(m1, off), So1 = __shfl_xor(S1, off), Po1 = __shfl_xor(P1, off);
    float nm = fmaxf(m0, mo0);
    float ea = __expf(m0 - nm), eb = __expf(mo0 - nm);
    S0 = S0 * ea + So0 * eb; P0 = P0 * ea + Po0 * eb; m0 = nm;
    nm = fmaxf(m1, mo1);
    ea = __expf(m1 - nm); eb = __expf(mo1 - nm);
    S1 = S1 * ea + So1 * eb; P1 = P1 * ea + Po1 * eb; m1 = nm;
  }

  if (lane < 16) {
    const int base = (int)blockIdx.y * NROWS + wrow0 + l15;
    pm[base] = m0; ps[base] = S0; pp[base] = P0;
    pm[base + 16] = m1; ps[base + 16] = S1; pp[base + 16] = P1;
  }
}

__global__ __launch_bounds__(256) void merge_kernel(
    const float* __restrict__ pm, const float* __restrict__ ps,
    const float* __restrict__ pp, const int* __restrict__ labels,
    const int* __restrict__ cnt, float* __restrict__ acc) {
  const int i = blockIdx.x * 256 + threadIdx.x;    // one thread per row
  float m = -3.0e38f;
#pragma unroll
  for (int c = 0; c < CSPLIT; ++c) m = fmaxf(m, pm[c * NROWS + i]);
  float S = 0.f, P = 0.f;
#pragma unroll
  for (int c = 0; c < CSPLIT; ++c) {
    const float sc = __expf(pm[c * NROWS + i] - m);
    S += ps[c * NROWS + i] * sc;
    P += pp[c * NROWS + i] * sc;
  }
  const int li = labels[i];
  const int pcnt = (li == 0) ? (NROWS - 1) : (cnt[li + 1] - 1 + cnt[1]);
  const bool valid = pcnt > 0;
  float loss = valid ? (-__logf((P + EPSV) / (S + EPSV))) : 0.f;
  float vc   = valid ? 1.f : 0.f;
#pragma unroll
  for (int off = 32; off > 0; off >>= 1) {
    loss += __shfl_down(loss, off);
    vc   += __shfl_down(vc, off);
  }
  if ((threadIdx.x & 63) == 0) {
    atomicAdd(&acc[0], loss);
    atomicAdd(&acc[1], vc);
  }
}

__global__ void final_kernel(const float* __restrict__ acc, float* __restrict__ out) {
  if (threadIdx.x == 0 && blockIdx.x == 0) {
    const float c = acc[1];
    out[0] = (c > 0.f) ? (acc[0] / c) : 0.f;
  }
}

extern "C" void kernel_launch(void* const* d_in, const int* in_sizes, int n_in,
                              void* d_out, int out_size, void* d_ws, size_t ws_size,
                              hipStream_t stream) {
  (void)in_sizes; (void)n_in; (void)out_size; (void)ws_size;
  const int*   labels = (const int*)d_in[0];
  const float* emb    = (const float*)d_in[1];

  char* ws = (char*)d_ws;
  u16*   ehi = (u16*)(ws);                                   // 2 MB
  u16*   elo = (u16*)(ws + (size_t)NROWS * DDIM * 2);        // 2 MB
  float* pm  = (float*)(ws + (size_t)2 * NROWS * DDIM * 2);  // 256 KB
  float* ps  = pm + CSPLIT * NROWS;                          // 256 KB
  float* pp  = ps + CSPLIT * NROWS;                          // 256 KB
  int*   cnt = (int*)(pp + CSPLIT * NROWS);                  // 4 ints
  float* acc = (float*)(cnt + 4);                            // 2 floats

  hipMemsetAsync(cnt, 0, 24, stream);
  prep_kernel<<<NROWS * DDIM / 8 / 256, 256, 0, stream>>>(emb, labels, ehi, elo, cnt);
  sim_kernel<<<dim3(NROWS / ROWB, CSPLIT), 256, 0, stream>>>(ehi, elo, labels, pm, ps, pp);
  merge_kernel<<<NROWS / 256, 256, 0, stream>>>(pm, ps, pp, labels, cnt, acc);
  final_kernel<<<1, 64, 0, stream>>>(acc, (float*)d_out);
}